// Round 1
// baseline (232.332 us; speedup 1.0000x reference)
//
#include <hip/hip_runtime.h>

#define LOG2PI_F 1.8378770664093453f

__global__ __launch_bounds__(256) void nll_kernel(
    const float* __restrict__ TF_high_mu,
    const float* __restrict__ TF_high_sigma,
    const float* __restrict__ TG_mu,
    const float* __restrict__ TG_sigma,
    const float* __restrict__ TF_high_exp,
    const float* __restrict__ TG_exp,
    const float* __restrict__ k_edge,
    const float* __restrict__ alpha,
    const float* __restrict__ cov,
    const float* __restrict__ edge_y,
    const float* __restrict__ edge_x,
    const int*  __restrict__ father_num,
    const int*  __restrict__ idx_tf_tg,
    const int*  __restrict__ idx_tf_high,
    const int*  __restrict__ edge_tg_idx,
    const int*  __restrict__ is_high,
    float* __restrict__ out,
    int n_tfh, int n_tg, int n_e)
{
    const int tid = blockIdx.x * blockDim.x + threadIdx.x;
    const int nth = gridDim.x * blockDim.x;

    // acc accumulates contributions to the FINAL output -(p + q + kterm):
    //   p terms contribute -lp
    //   q = -sum((fn-1)*lp)  =>  -(q) contributes +(fn-1)*lp
    //   edge terms contribute -lp
    float acc = 0.0f;

    // ---- p term (N=1000)
    for (int i = tid; i < n_tfh; i += nth) {
        float sig = TF_high_sigma[i];
        float z = (TF_high_exp[i] - TF_high_mu[i]) / sig;
        float lp = -0.5f * z * z - __logf(sig) - 0.5f * LOG2PI_F;
        acc -= lp;
    }

    // ---- q term (N=20000)
    for (int i = tid; i < n_tg; i += nth) {
        float sig = TG_sigma[i];
        float z = (TG_exp[i] - TG_mu[i]) / sig;
        float lp = -0.5f * z * z - __logf(sig) - 0.5f * LOG2PI_F;
        acc += ((float)father_num[i] - 1.0f) * lp;
    }

    // ---- edge term (N=4,000,000), vectorized x4
    auto edge_contrib = [&](float kk, float aa, float cc, float yy, float xx,
                            int hi, int iH, int iT, int iG) {
        // both gathers are always in-bounds; tables are L1/L2 resident
        float tfmu  = hi ? TF_high_mu[iH]    : TG_mu[iT];
        float tfsig = hi ? TF_high_sigma[iH] : TG_sigma[iT];
        float tgmu  = TG_mu[iG];
        float tgsig = TG_sigma[iG];
        float ivar  = 1.0f / (tfsig * tfsig);
        float loc   = fmaxf(fmaf(kk * cc, (yy - tfmu) * ivar, tgmu), 0.0f) + 0.01f;
        float v     = fmaxf(fmaf(-aa * aa, ivar, tgsig * tgsig), 0.0f) + 0.01f;
        float d     = xx - loc;
        // log(scale) = 0.5*log(v): avoids the sqrt entirely
        float lp    = -0.5f * d * d / v - 0.5f * __logf(v) - 0.5f * LOG2PI_F;
        acc -= lp;
    };

    const int nvec = n_e >> 2;
    const float4* k4 = (const float4*)k_edge;
    const float4* a4 = (const float4*)alpha;
    const float4* c4 = (const float4*)cov;
    const float4* y4 = (const float4*)edge_y;
    const float4* x4 = (const float4*)edge_x;
    const int4*  ih4 = (const int4*)is_high;
    const int4*  iH4 = (const int4*)idx_tf_high;
    const int4*  iT4 = (const int4*)idx_tf_tg;
    const int4*  iG4 = (const int4*)edge_tg_idx;

    for (int i = tid; i < nvec; i += nth) {
        float4 k = k4[i], a = a4[i], c = c4[i], y = y4[i], x = x4[i];
        int4  ih = ih4[i], iH = iH4[i], iT = iT4[i], iG = iG4[i];
        edge_contrib(k.x, a.x, c.x, y.x, x.x, ih.x, iH.x, iT.x, iG.x);
        edge_contrib(k.y, a.y, c.y, y.y, x.y, ih.y, iH.y, iT.y, iG.y);
        edge_contrib(k.z, a.z, c.z, y.z, x.z, ih.z, iH.z, iT.z, iG.z);
        edge_contrib(k.w, a.w, c.w, y.w, x.w, ih.w, iH.w, iT.w, iG.w);
    }
    // tail (n_e not divisible by 4)
    for (int i = (nvec << 2) + tid; i < n_e; i += nth) {
        edge_contrib(k_edge[i], alpha[i], cov[i], edge_y[i], edge_x[i],
                     is_high[i], idx_tf_high[i], idx_tf_tg[i], edge_tg_idx[i]);
    }

    // ---- reduction: wave64 shuffle -> LDS across 4 waves -> 1 atomic/block
    #pragma unroll
    for (int off = 32; off > 0; off >>= 1)
        acc += __shfl_down(acc, off, 64);

    __shared__ float wave_sums[4];
    const int lane = threadIdx.x & 63;
    const int wave = threadIdx.x >> 6;
    if (lane == 0) wave_sums[wave] = acc;
    __syncthreads();
    if (threadIdx.x == 0) {
        float s = wave_sums[0] + wave_sums[1] + wave_sums[2] + wave_sums[3];
        atomicAdd(out, s);
    }
}

extern "C" void kernel_launch(void* const* d_in, const int* in_sizes, int n_in,
                              void* d_out, int out_size, void* d_ws, size_t ws_size,
                              hipStream_t stream)
{
    const float* TF_high_mu    = (const float*)d_in[0];
    const float* TF_high_sigma = (const float*)d_in[1];
    const float* TG_mu         = (const float*)d_in[2];
    const float* TG_sigma      = (const float*)d_in[3];
    const float* TF_high_exp   = (const float*)d_in[4];
    const float* TG_exp        = (const float*)d_in[5];
    const float* k_edge        = (const float*)d_in[6];
    const float* alpha         = (const float*)d_in[7];
    const float* cov           = (const float*)d_in[8];
    const float* edge_y        = (const float*)d_in[9];
    const float* edge_x        = (const float*)d_in[10];
    const int*  father_num     = (const int*)d_in[11];
    const int*  idx_tf_tg      = (const int*)d_in[12];
    const int*  idx_tf_high    = (const int*)d_in[13];
    const int*  edge_tg_idx    = (const int*)d_in[14];
    const int*  is_high        = (const int*)d_in[15];

    const int n_tfh = in_sizes[0];
    const int n_tg  = in_sizes[2];
    const int n_e   = in_sizes[6];

    // d_out is poisoned 0xAA before every launch — zero it (capture-safe)
    hipMemsetAsync(d_out, 0, sizeof(float), stream);

    const int threads = 256;
    const int blocks  = 4096;  // 1M threads: ~1 float4-edge iter each; mem-bound
    hipLaunchKernelGGL(nll_kernel, dim3(blocks), dim3(threads), 0, stream,
                       TF_high_mu, TF_high_sigma, TG_mu, TG_sigma,
                       TF_high_exp, TG_exp, k_edge, alpha, cov, edge_y, edge_x,
                       father_num, idx_tf_tg, idx_tf_high, edge_tg_idx, is_high,
                       (float*)d_out, n_tfh, n_tg, n_e);
}

// Round 2
// 215.475 us; speedup vs baseline: 1.0782x; 1.0782x over previous
//
#include <hip/hip_runtime.h>

#define LOG2PI_F 1.8378770664093453f

// ---------------------------------------------------------------------------
// Prologue: pack (mu,sigma) tables into float2 for single-load gathers, and
// fold the tiny p/q reductions plus the per-edge 0.5*log2pi constant into out.
// ---------------------------------------------------------------------------
__global__ __launch_bounds__(256) void pack_kernel(
    const float* __restrict__ TF_high_mu,
    const float* __restrict__ TF_high_sigma,
    const float* __restrict__ TG_mu,
    const float* __restrict__ TG_sigma,
    const float* __restrict__ TF_high_exp,
    const float* __restrict__ TG_exp,
    const int*  __restrict__ father_num,
    float2* __restrict__ tf_pack,   // [n_tfh]
    float2* __restrict__ tg_pack,   // [n_tg]
    float* __restrict__ out,
    int n_tfh, int n_tg, int n_e)
{
    const int tid = blockIdx.x * blockDim.x + threadIdx.x;
    const int nth = gridDim.x * blockDim.x;

    float acc = 0.0f;

    for (int i = tid; i < n_tfh; i += nth) {
        float mu = TF_high_mu[i], sig = TF_high_sigma[i];
        tf_pack[i] = make_float2(mu, sig);
        float z = (TF_high_exp[i] - mu) / sig;
        float lp = -0.5f * z * z - __logf(sig) - 0.5f * LOG2PI_F;
        acc -= lp;                              // contributes -p
    }

    for (int i = tid; i < n_tg; i += nth) {
        float mu = TG_mu[i], sig = TG_sigma[i];
        tg_pack[i] = make_float2(mu, sig);
        float z = (TG_exp[i] - mu) / sig;
        float lp = -0.5f * z * z - __logf(sig) - 0.5f * LOG2PI_F;
        acc += ((float)father_num[i] - 1.0f) * lp;   // contributes -q
    }

    // fold the edge-term constant once: each edge contributes +0.5*log2pi
    if (tid == 0) acc += 0.5f * LOG2PI_F * (float)n_e;

    #pragma unroll
    for (int off = 32; off > 0; off >>= 1)
        acc += __shfl_down(acc, off, 64);

    __shared__ float wave_sums[4];
    const int lane = threadIdx.x & 63;
    const int wave = threadIdx.x >> 6;
    if (lane == 0) wave_sums[wave] = acc;
    __syncthreads();
    if (threadIdx.x == 0) {
        float s = wave_sums[0] + wave_sums[1] + wave_sums[2] + wave_sums[3];
        atomicAdd(out, s);
    }
}

// ---------------------------------------------------------------------------
// Main: edge term. 9 contiguous 16B streams + 2 scattered 8B gathers/edge.
// ---------------------------------------------------------------------------
__global__ __launch_bounds__(256) void edge_kernel(
    const float2* __restrict__ tf_pack,
    const float2* __restrict__ tg_pack,
    const float* __restrict__ k_edge,
    const float* __restrict__ alpha,
    const float* __restrict__ cov,
    const float* __restrict__ edge_y,
    const float* __restrict__ edge_x,
    const int*  __restrict__ idx_tf_tg,
    const int*  __restrict__ idx_tf_high,
    const int*  __restrict__ edge_tg_idx,
    const int*  __restrict__ is_high,
    float* __restrict__ out,
    int n_e)
{
    const int tid = blockIdx.x * blockDim.x + threadIdx.x;
    const int nth = gridDim.x * blockDim.x;

    float acc = 0.0f;   // accumulates -(lp + 0.5*log2pi) per edge

    const int nvec = n_e >> 2;
    const float4* k4 = (const float4*)k_edge;
    const float4* a4 = (const float4*)alpha;
    const float4* c4 = (const float4*)cov;
    const float4* y4 = (const float4*)edge_y;
    const float4* x4 = (const float4*)edge_x;
    const int4*  ih4 = (const int4*)is_high;
    const int4*  iH4 = (const int4*)idx_tf_high;
    const int4*  iT4 = (const int4*)idx_tf_tg;
    const int4*  iG4 = (const int4*)edge_tg_idx;

    for (int i = tid; i < nvec; i += nth) {
        int4 ih = ih4[i], iH = iH4[i], iT = iT4[i], iG = iG4[i];

        // issue all 8 scattered gathers up front (max MLP, no dependent math)
        const float2* b0 = ih.x ? tf_pack : tg_pack;
        const float2* b1 = ih.y ? tf_pack : tg_pack;
        const float2* b2 = ih.z ? tf_pack : tg_pack;
        const float2* b3 = ih.w ? tf_pack : tg_pack;
        float2 tf0 = b0[ih.x ? iH.x : iT.x];
        float2 tf1 = b1[ih.y ? iH.y : iT.y];
        float2 tf2 = b2[ih.z ? iH.z : iT.z];
        float2 tf3 = b3[ih.w ? iH.w : iT.w];
        float2 tg0 = tg_pack[iG.x];
        float2 tg1 = tg_pack[iG.y];
        float2 tg2 = tg_pack[iG.z];
        float2 tg3 = tg_pack[iG.w];

        float4 k = k4[i], a = a4[i], c = c4[i], y = y4[i], x = x4[i];

        auto edge = [&](float kk, float aa, float cc, float yy, float xx,
                        float2 tf, float2 tg) {
            float ivar = 1.0f / (tf.y * tf.y);
            float loc  = fmaxf(fmaf(kk * cc, (yy - tf.x) * ivar, tg.x), 0.0f) + 0.01f;
            float v    = fmaxf(fmaf(-aa * aa, ivar, tg.y * tg.y), 0.0f) + 0.01f;
            float d    = xx - loc;
            // -lp - 0.5*log2pi = 0.5*d*d/v + 0.5*log(v)
            acc += 0.5f * (d * d / v + __logf(v));
        };
        edge(k.x, a.x, c.x, y.x, x.x, tf0, tg0);
        edge(k.y, a.y, c.y, y.y, x.y, tf1, tg1);
        edge(k.z, a.z, c.z, y.z, x.z, tf2, tg2);
        edge(k.w, a.w, c.w, y.w, x.w, tf3, tg3);
    }

    // tail (n_e not divisible by 4)
    for (int i = (nvec << 2) + tid; i < n_e; i += nth) {
        float2 tf = is_high[i] ? ((const float2*)tf_pack)[idx_tf_high[i]]
                               : ((const float2*)tg_pack)[idx_tf_tg[i]];
        float2 tg = tg_pack[edge_tg_idx[i]];
        float ivar = 1.0f / (tf.y * tf.y);
        float loc  = fmaxf(fmaf(k_edge[i] * cov[i], (edge_y[i] - tf.x) * ivar, tg.x), 0.0f) + 0.01f;
        float v    = fmaxf(fmaf(-alpha[i] * alpha[i], ivar, tg.y * tg.y), 0.0f) + 0.01f;
        float d    = edge_x[i] - loc;
        acc += 0.5f * (d * d / v + __logf(v));
    }

    #pragma unroll
    for (int off = 32; off > 0; off >>= 1)
        acc += __shfl_down(acc, off, 64);

    __shared__ float wave_sums[4];
    const int lane = threadIdx.x & 63;
    const int wave = threadIdx.x >> 6;
    if (lane == 0) wave_sums[wave] = acc;
    __syncthreads();
    if (threadIdx.x == 0) {
        float s = wave_sums[0] + wave_sums[1] + wave_sums[2] + wave_sums[3];
        atomicAdd(out, s);
    }
}

extern "C" void kernel_launch(void* const* d_in, const int* in_sizes, int n_in,
                              void* d_out, int out_size, void* d_ws, size_t ws_size,
                              hipStream_t stream)
{
    const float* TF_high_mu    = (const float*)d_in[0];
    const float* TF_high_sigma = (const float*)d_in[1];
    const float* TG_mu         = (const float*)d_in[2];
    const float* TG_sigma      = (const float*)d_in[3];
    const float* TF_high_exp   = (const float*)d_in[4];
    const float* TG_exp        = (const float*)d_in[5];
    const float* k_edge        = (const float*)d_in[6];
    const float* alpha         = (const float*)d_in[7];
    const float* cov           = (const float*)d_in[8];
    const float* edge_y        = (const float*)d_in[9];
    const float* edge_x        = (const float*)d_in[10];
    const int*  father_num     = (const int*)d_in[11];
    const int*  idx_tf_tg      = (const int*)d_in[12];
    const int*  idx_tf_high    = (const int*)d_in[13];
    const int*  edge_tg_idx    = (const int*)d_in[14];
    const int*  is_high        = (const int*)d_in[15];

    const int n_tfh = in_sizes[0];
    const int n_tg  = in_sizes[2];
    const int n_e   = in_sizes[6];

    // workspace layout: [tf_pack: n_tfh float2][tg_pack: n_tg float2]
    float2* tf_pack = (float2*)d_ws;
    float2* tg_pack = tf_pack + n_tfh;

    // d_out poisoned 0xAA each launch — zero it (capture-safe)
    hipMemsetAsync(d_out, 0, sizeof(float), stream);

    hipLaunchKernelGGL(pack_kernel, dim3(84), dim3(256), 0, stream,
                       TF_high_mu, TF_high_sigma, TG_mu, TG_sigma,
                       TF_high_exp, TG_exp, father_num,
                       tf_pack, tg_pack, (float*)d_out, n_tfh, n_tg, n_e);

    const int threads = 256;
    const int blocks  = 4096;
    hipLaunchKernelGGL(edge_kernel, dim3(blocks), dim3(threads), 0, stream,
                       tf_pack, tg_pack, k_edge, alpha, cov, edge_y, edge_x,
                       idx_tf_tg, idx_tf_high, edge_tg_idx, is_high,
                       (float*)d_out, n_e);
}

// Round 3
// 196.029 us; speedup vs baseline: 1.1852x; 1.0992x over previous
//
#include <hip/hip_runtime.h>
#include <hip/hip_fp16.h>

#define LOG2PI_F 1.8378770664093453f

// Fixed problem sizes (reference: N_TFH=1000, N_TG=20000). The combined
// gather table holds TG entries at [0, N_TG) and TF_high entries at
// [N_TG, N_TG+N_TFH).
#define N_TG_C   20000
#define N_TFH_C  1000
#define N_TOT_C  (N_TG_C + N_TFH_C)          // 21000 entries
#define MU_BYTES (N_TOT_C * 2)               // 42000 B (fp16)
#define SG_BYTES (N_TOT_C)                   // 21000 B (u8)

// ---------------------------------------------------------------------------
// Prologue: build quantized combined table in ws, fold p/q terms + the
// per-edge 0.5*log2pi constant into out.
//   ws layout: [mu: u16 x 21000][sig: u8 x 21000]
// ---------------------------------------------------------------------------
__global__ __launch_bounds__(256) void pack_kernel(
    const float* __restrict__ TF_high_mu,
    const float* __restrict__ TF_high_sigma,
    const float* __restrict__ TG_mu,
    const float* __restrict__ TG_sigma,
    const float* __restrict__ TF_high_exp,
    const float* __restrict__ TG_exp,
    const int*  __restrict__ father_num,
    unsigned short* __restrict__ ws_mu,
    unsigned char*  __restrict__ ws_sig,
    float* __restrict__ out,
    int n_tfh, int n_tg, int n_e)
{
    const int tid = blockIdx.x * blockDim.x + threadIdx.x;
    const int nth = gridDim.x * blockDim.x;

    float acc = 0.0f;

    for (int i = tid; i < n_tg; i += nth) {
        float mu = TG_mu[i], sig = TG_sigma[i];
        ws_mu[i] = __half_as_ushort(__float2half(mu));
        float q = (sig - 0.5f) * 255.0f;
        q = fminf(fmaxf(q, 0.0f), 255.0f);
        ws_sig[i] = (unsigned char)lrintf(q);
        // q term (full fp32 precision)
        float z = (TG_exp[i] - mu) / sig;
        float lp = -0.5f * z * z - __logf(sig) - 0.5f * LOG2PI_F;
        acc += ((float)father_num[i] - 1.0f) * lp;   // contributes -q
    }

    for (int i = tid; i < n_tfh; i += nth) {
        float mu = TF_high_mu[i], sig = TF_high_sigma[i];
        ws_mu[N_TG_C + i] = __half_as_ushort(__float2half(mu));
        float q = (sig - 0.5f) * 255.0f;
        q = fminf(fmaxf(q, 0.0f), 255.0f);
        ws_sig[N_TG_C + i] = (unsigned char)lrintf(q);
        // p term
        float z = (TF_high_exp[i] - mu) / sig;
        float lp = -0.5f * z * z - __logf(sig) - 0.5f * LOG2PI_F;
        acc -= lp;                                   // contributes -p
    }

    // each edge contributes +0.5*log2pi to the final negated sum; fold once
    if (tid == 0) acc += 0.5f * LOG2PI_F * (float)n_e;

    #pragma unroll
    for (int off = 32; off > 0; off >>= 1)
        acc += __shfl_down(acc, off, 64);

    __shared__ float wave_sums[4];
    const int lane = threadIdx.x & 63;
    const int wave = threadIdx.x >> 6;
    if (lane == 0) wave_sums[wave] = acc;
    __syncthreads();
    if (threadIdx.x == 0) {
        float s = wave_sums[0] + wave_sums[1] + wave_sums[2] + wave_sums[3];
        atomicAdd(out, s);
    }
}

// ---------------------------------------------------------------------------
// Main: edge term. All gathers served from LDS (random-bank, off the vmem
// pipe); vmem does only 9 coalesced 16B streams per thread-group.
// ---------------------------------------------------------------------------
__global__ __launch_bounds__(256) void edge_kernel(
    const unsigned short* __restrict__ ws_mu,
    const unsigned char*  __restrict__ ws_sig,
    const float* __restrict__ k_edge,
    const float* __restrict__ alpha,
    const float* __restrict__ cov,
    const float* __restrict__ edge_y,
    const float* __restrict__ edge_x,
    const int*  __restrict__ idx_tf_tg,
    const int*  __restrict__ idx_tf_high,
    const int*  __restrict__ edge_tg_idx,
    const int*  __restrict__ is_high,
    float* __restrict__ out,
    int n_e)
{
    __shared__ unsigned short s_mu[N_TOT_C];   // 42000 B
    __shared__ unsigned char  s_sig[N_TOT_C];  // 21000 B
    __shared__ float wave_sums[4];             // total ~63 KB -> 2 blocks/CU

    // cooperative fill from the packed ws tables (u32 copies, coalesced)
    {
        const uint32_t* src_mu = (const uint32_t*)ws_mu;
        uint32_t* dst_mu = (uint32_t*)s_mu;
        for (int w = threadIdx.x; w < MU_BYTES / 4; w += 256) dst_mu[w] = src_mu[w];
        const uint32_t* src_sg = (const uint32_t*)ws_sig;
        uint32_t* dst_sg = (uint32_t*)s_sig;
        for (int w = threadIdx.x; w < SG_BYTES / 4; w += 256) dst_sg[w] = src_sg[w];
    }
    __syncthreads();

    const int tid = blockIdx.x * blockDim.x + threadIdx.x;
    const int nth = gridDim.x * blockDim.x;

    float acc = 0.0f;   // accumulates -(lp + 0.5*log2pi) per edge

    const int nvec = n_e >> 2;
    const float4* k4 = (const float4*)k_edge;
    const float4* a4 = (const float4*)alpha;
    const float4* c4 = (const float4*)cov;
    const float4* y4 = (const float4*)edge_y;
    const float4* x4 = (const float4*)edge_x;
    const int4*  ih4 = (const int4*)is_high;
    const int4*  iH4 = (const int4*)idx_tf_high;
    const int4*  iT4 = (const int4*)idx_tf_tg;
    const int4*  iG4 = (const int4*)edge_tg_idx;

    auto edge = [&](float kk, float aa, float cc, float yy, float xx,
                    int tf_idx, int tg_idx) {
        float tfmu  = __half2float(__ushort_as_half(s_mu[tf_idx]));
        float tfsig = fmaf((float)s_sig[tf_idx], 1.0f / 255.0f, 0.5f);
        float tgmu  = __half2float(__ushort_as_half(s_mu[tg_idx]));
        float tgsig = fmaf((float)s_sig[tg_idx], 1.0f / 255.0f, 0.5f);
        float ivar = 1.0f / (tfsig * tfsig);
        float loc  = fmaxf(fmaf(kk * cc, (yy - tfmu) * ivar, tgmu), 0.0f) + 0.01f;
        float v    = fmaxf(fmaf(-aa * aa, ivar, tgsig * tgsig), 0.0f) + 0.01f;
        float d    = xx - loc;
        // -lp - 0.5*log2pi = 0.5*(d*d/v + log(v))
        acc += 0.5f * (d * d / v + __logf(v));
    };

    for (int i = tid; i < nvec; i += nth) {
        int4 ih = ih4[i], iH = iH4[i], iT = iT4[i], iG = iG4[i];
        // branchless combined-table index: TF_high entries live at +N_TG
        int t0 = ih.x ? (N_TG_C + iH.x) : iT.x;
        int t1 = ih.y ? (N_TG_C + iH.y) : iT.y;
        int t2 = ih.z ? (N_TG_C + iH.z) : iT.z;
        int t3 = ih.w ? (N_TG_C + iH.w) : iT.w;

        float4 k = k4[i], a = a4[i], c = c4[i], y = y4[i], x = x4[i];

        edge(k.x, a.x, c.x, y.x, x.x, t0, iG.x);
        edge(k.y, a.y, c.y, y.y, x.y, t1, iG.y);
        edge(k.z, a.z, c.z, y.z, x.z, t2, iG.z);
        edge(k.w, a.w, c.w, y.w, x.w, t3, iG.w);
    }

    // tail (n_e not divisible by 4)
    for (int i = (nvec << 2) + tid; i < n_e; i += nth) {
        int t = is_high[i] ? (N_TG_C + idx_tf_high[i]) : idx_tf_tg[i];
        edge(k_edge[i], alpha[i], cov[i], edge_y[i], edge_x[i], t, edge_tg_idx[i]);
    }

    #pragma unroll
    for (int off = 32; off > 0; off >>= 1)
        acc += __shfl_down(acc, off, 64);

    const int lane = threadIdx.x & 63;
    const int wave = threadIdx.x >> 6;
    if (lane == 0) wave_sums[wave] = acc;
    __syncthreads();
    if (threadIdx.x == 0) {
        float s = wave_sums[0] + wave_sums[1] + wave_sums[2] + wave_sums[3];
        atomicAdd(out, s);
    }
}

extern "C" void kernel_launch(void* const* d_in, const int* in_sizes, int n_in,
                              void* d_out, int out_size, void* d_ws, size_t ws_size,
                              hipStream_t stream)
{
    const float* TF_high_mu    = (const float*)d_in[0];
    const float* TF_high_sigma = (const float*)d_in[1];
    const float* TG_mu         = (const float*)d_in[2];
    const float* TG_sigma      = (const float*)d_in[3];
    const float* TF_high_exp   = (const float*)d_in[4];
    const float* TG_exp        = (const float*)d_in[5];
    const float* k_edge        = (const float*)d_in[6];
    const float* alpha         = (const float*)d_in[7];
    const float* cov           = (const float*)d_in[8];
    const float* edge_y        = (const float*)d_in[9];
    const float* edge_x        = (const float*)d_in[10];
    const int*  father_num     = (const int*)d_in[11];
    const int*  idx_tf_tg      = (const int*)d_in[12];
    const int*  idx_tf_high    = (const int*)d_in[13];
    const int*  edge_tg_idx    = (const int*)d_in[14];
    const int*  is_high        = (const int*)d_in[15];

    const int n_tfh = in_sizes[0];
    const int n_tg  = in_sizes[2];
    const int n_e   = in_sizes[6];

    // ws layout: [mu: u16 x 21000][sig: u8 x 21000]
    unsigned short* ws_mu  = (unsigned short*)d_ws;
    unsigned char*  ws_sig = (unsigned char*)d_ws + MU_BYTES;

    // d_out poisoned 0xAA each launch — zero it (capture-safe)
    hipMemsetAsync(d_out, 0, sizeof(float), stream);

    hipLaunchKernelGGL(pack_kernel, dim3(84), dim3(256), 0, stream,
                       TF_high_mu, TF_high_sigma, TG_mu, TG_sigma,
                       TF_high_exp, TG_exp, father_num,
                       ws_mu, ws_sig, (float*)d_out, n_tfh, n_tg, n_e);

    // 512 blocks = 2 blocks/CU (63 KB LDS each); ~7.6 float4-groups/thread
    hipLaunchKernelGGL(edge_kernel, dim3(512), dim3(256), 0, stream,
                       ws_mu, ws_sig, k_edge, alpha, cov, edge_y, edge_x,
                       idx_tf_tg, idx_tf_high, edge_tg_idx, is_high,
                       (float*)d_out, n_e);
}